// Round 9
// baseline (355.446 us; speedup 1.0000x reference)
//
#include <hip/hip_runtime.h>
#include <hip/hip_bf16.h>

// Effi_MVS: B=1, V=5, C=32, D=48, H=128, W=160, RATIO=8.
// Round 12: the warp is a uniform x-shift per (view,depth): gx = x + 400v/d,
// gy = y (runtime-verified per thread; general fallback kept). Exploit:
//   - k_pad: features -> x-padded [5][32][128][168] (edge-replicated) so the
//     fast path has NO clamping.
//   - k_gather: thread = 4 consecutive px x 8 channels (DHW threads, 60
//     waves/CU preserved). Per view per channel: ONE dwordx4 at +off (off in
//     the address, static extraction) + one dword => 9 loads / (4px*ch) vs 20.
//     Weights per-pixel exact. var -> pair-interleaved u32[16][DHW], 16B
//     lane-contiguous stores (fixes R11's 64-line store pattern).
//   - k_contract: R11's HW-verified MFMA contraction, pair-layout A-frags.
//   - conv scalar + upsample 8-out + softmax: R6-proven others (102us).
// fpad aliases WV region (dead before k_contract writes WV): ws stays 120MB.

#define NV 5
#define NC 32
#define ND 48
#define NH 128
#define NW 160
#define HW (NH * NW)
#define DHW (ND * HW)
#define WPAD 168
#define HWP (NH * WPAD)   // 21504 floats per plane

typedef __attribute__((ext_vector_type(2))) float f32x2;
typedef __attribute__((ext_vector_type(4))) float f32x4;
typedef __attribute__((ext_vector_type(4), aligned(4))) float f32x4u;
typedef __attribute__((ext_vector_type(8))) short short8;
typedef __attribute__((ext_vector_type(4))) unsigned int u32x4;

// ws layout (bytes)
#define OFF_M      0          // float M[4][12]
#define OFF_WFB    256        // bf16 wfB[2][64][8] = 2048
#define OFF_DEPTHF 4096       // float depthf[20480]            (end 86,016)
#define OFF_PRE    86016      // float pre[DHW] = 3,932,160     (end 4,018,176)
#define OFF_WV     4018176    // bf16 WV[27][DHW] = 53,084,160  (end 57,102,336)
#define OFF_FPAD   4018176    // float fpad[5][32][128][168] = 13,762,560
                              //   ALIASES WV: dead before k_contract writes
#define OFF_VARP   57102336   // u32 varP[16][DHW] = 62,914,560 (end 120,016,896)
// total = 120,016,896 bytes (same as R11, proven available)

__device__ __forceinline__ uint32_t pack_bf16(float a, float b) {
  __hip_bfloat16 ba = __float2bfloat16(a), bb = __float2bfloat16(b);
  uint16_t ua, ub;
  __builtin_memcpy(&ua, &ba, 2);
  __builtin_memcpy(&ub, &bb, 2);
  return (uint32_t)ua | ((uint32_t)ub << 16);
}

// ---------------------------------------------------------------- K1: setup
__global__ void k_setup(const float* __restrict__ proj,
                        const float* __restrict__ wreg,
                        float* __restrict__ M,
                        unsigned short* __restrict__ wfB) {
  if (threadIdx.x != 0) return;
  double P[NV][2][4][4];
  for (int v = 0; v < NV; ++v)
    for (int m = 0; m < 2; ++m)
      for (int i = 0; i < 4; ++i)
        for (int j = 0; j < 4; ++j)
          P[v][m][i][j] = (double)proj[((v * 2 + m) * 4 + i) * 4 + j];
  double C[NV][4][4];
  for (int v = 0; v < NV; ++v) {
    for (int i = 0; i < 4; ++i)
      for (int j = 0; j < 4; ++j) C[v][i][j] = P[v][0][i][j];
    for (int i = 0; i < 3; ++i)
      for (int j = 0; j < 4; ++j) {
        double s = 0.0;
        for (int k = 0; k < 3; ++k) s += P[v][1][i][k] * P[v][0][k][j];
        C[v][i][j] = s;
      }
  }
  double a[4][8];
  for (int i = 0; i < 4; ++i)
    for (int j = 0; j < 4; ++j) { a[i][j] = C[0][i][j]; a[i][j + 4] = (i == j) ? 1.0 : 0.0; }
  for (int col = 0; col < 4; ++col) {
    int piv = col; double best = fabs(a[col][col]);
    for (int r = col + 1; r < 4; ++r) { double v = fabs(a[r][col]); if (v > best) { best = v; piv = r; } }
    if (piv != col)
      for (int j = 0; j < 8; ++j) { double t = a[col][j]; a[col][j] = a[piv][j]; a[piv][j] = t; }
    double pv = a[col][col];
    for (int j = 0; j < 8; ++j) a[col][j] /= pv;
    for (int r = 0; r < 4; ++r) if (r != col) {
      double f = a[r][col];
      for (int j = 0; j < 8; ++j) a[r][j] -= f * a[col][j];
    }
  }
  double inv[4][4];
  for (int i = 0; i < 4; ++i)
    for (int j = 0; j < 4; ++j) inv[i][j] = a[i][j + 4];
  for (int v = 1; v < NV; ++v) {
    float* m = M + (v - 1) * 12;
    for (int i = 0; i < 3; ++i) {
      double r[4] = {0, 0, 0, 0};
      for (int k = 0; k < 4; ++k) {
        double cv = C[v][i][k];
        for (int j = 0; j < 4; ++j) r[j] += cv * inv[k][j];
      }
      m[i * 3 + 0] = (float)r[0]; m[i * 3 + 1] = (float)r[1]; m[i * 3 + 2] = (float)r[2];
      m[9 + i] = (float)r[3];
    }
  }
  // B-fragment layout for mfma_f32_16x16x32_bf16 (HW-verified R9/R11):
  // lane l supplies col n = l&15 (tap), k = (l>>4)*8 + e
  for (int nt = 0; nt < 2; ++nt)
    for (int l = 0; l < 64; ++l)
      for (int e = 0; e < 8; ++e) {
        int tap = nt * 16 + (l & 15);
        int k = (l >> 4) * 8 + e;
        float val = (tap < 27) ? wreg[k * 27 + tap] : 0.f;
        __hip_bfloat16 b = __float2bfloat16(val);
        uint16_t u; __builtin_memcpy(&u, &b, 2);
        wfB[(nt * 64 + l) * 8 + e] = u;
      }
}

// ---------------------------------------------- K1b: x-pad feature planes
__global__ __launch_bounds__(256) void k_pad(const float* __restrict__ feat,
                                             float* __restrict__ fpad) {
  int i = blockIdx.x * 256 + threadIdx.x;   // [0, 5*32*128*168)
  int xp = i % WPAD;
  int r = i / WPAD;                          // (v*32+c)*128 + y
  int x = min(xp, NW - 1);
  fpad[i] = feat[r * NW + x];
}

// ------------------------------------ K2a: gather + variance (4px x 8ch)
__global__ __launch_bounds__(256) void k_gather(
    const float* __restrict__ fpad,    // [5][32][128][168]
    const float* __restrict__ depthv,  // [48]
    const float* __restrict__ M,       // [4][12]
    uint32_t* __restrict__ varP)       // [16][DHW] bf16-pair per voxel
{
  int idx = blockIdx.x * 256 + threadIdx.x;   // [0, DHW)
  int cg = idx / (DHW / 4);                   // 0..3 (8 channels each)
  int r  = idx % (DHW / 4);
  int d  = r / (HW / 4);
  int p  = r % (HW / 4);
  int y  = p / (NW / 4);
  int x4 = (p % (NW / 4)) * 4;
  float yf = (float)y;
  float df = depthv[d];
  int c0 = cg * 8;
  int vox4 = d * HW + y * NW + x4;

  int rowv[4], offv[4];
  float w0[4][4], w1[4][4];
  bool fast = true;

#pragma unroll
  for (int v = 0; v < 4; ++v) {
    const float* m = M + v * 12;
    int oj[4], rj[4];
#pragma unroll
    for (int j = 0; j < 4; ++j) {
      float xf = (float)(x4 + j);
      float rx = m[0] * xf + m[1] * yf + m[2];
      float ry = m[3] * xf + m[4] * yf + m[5];
      float rz = m[6] * xf + m[7] * yf + m[8];
      float px = rx * df + m[9];
      float py = ry * df + m[10];
      float pz = rz * df + m[11];
      float gx = px / pz;
      float gy = py / pz;
      float y0 = floorf(gy);
      float wy = gy - y0;
      bool two = (wy == 0.f) || (wy == 1.f);
      float rowf = (wy == 0.f) ? y0 : (y0 + 1.f);
      float x0 = floorf(gx);
      float wx = gx - x0;
      bool v0 = (x0 >= 0.f) && (x0 <= (float)(NW - 1));
      bool v1 = (x0 + 1.f >= 0.f) && (x0 + 1.f <= (float)(NW - 1));
      w0[v][j] = (1.f - wx) * (v0 ? 1.f : 0.f);
      w1[v][j] = wx * (v1 ? 1.f : 0.f);
      oj[j] = (int)x0 - (x4 + j);            // shift (may be garbage if !two)
      rj[j] = (int)rowf;
      fast = fast && two;
    }
    fast = fast && (oj[0] == oj[1]) && (oj[1] == oj[2]) && (oj[2] == oj[3]) &&
           (rj[0] == rj[1]) && (rj[1] == rj[2]) && (rj[2] == rj[3]) &&
           (oj[0] >= 0) && (oj[0] <= 3) && (rj[0] >= 0) && (rj[0] <= NH - 1);
    offv[v] = oj[0];
    rowv[v] = rj[0];
  }

  uint32_t* vdst = varP + vox4;   // + pg*DHW per pair

  if (__builtin_expect(fast, 1)) {
    const float* bref = fpad + (size_t)c0 * HWP + y * WPAD + x4;
    const float* bv[4];
#pragma unroll
    for (int v = 0; v < 4; ++v)
      bv[v] = fpad + (size_t)((v + 1) * NC + c0) * HWP + rowv[v] * WPAD + x4 + offv[v];

#pragma unroll
    for (int pp = 0; pp < 4; ++pp) {          // channel pair within group
      float vr[2][4];
#pragma unroll
      for (int cc = 0; cc < 2; ++cc) {
        int cl = pp * 2 + cc;                 // channel offset within group
        f32x4 ref = *(const f32x4*)(bref + (size_t)cl * HWP);
        f32x4 vs = ref;
        f32x4 vq = ref * ref;
#pragma unroll
        for (int v = 0; v < 4; ++v) {
          const float* ptr = bv[v] + (size_t)cl * HWP;
          f32x4u A = *(const f32x4u*)ptr;
          float E = ptr[4];
          f32x4 val;
          val.x = w0[v][0] * A.x + w1[v][0] * A.y;
          val.y = w0[v][1] * A.y + w1[v][1] * A.z;
          val.z = w0[v][2] * A.z + w1[v][2] * A.w;
          val.w = w0[v][3] * A.w + w1[v][3] * E;
          vs += val;
          vq += val * val;
        }
        vr[cc][0] = vq.x * 0.2f - (vs.x * 0.2f) * (vs.x * 0.2f);
        vr[cc][1] = vq.y * 0.2f - (vs.y * 0.2f) * (vs.y * 0.2f);
        vr[cc][2] = vq.z * 0.2f - (vs.z * 0.2f) * (vs.z * 0.2f);
        vr[cc][3] = vq.w * 0.2f - (vs.w * 0.2f) * (vs.w * 0.2f);
      }
      u32x4 pk;
      pk.x = pack_bf16(vr[0][0], vr[1][0]);
      pk.y = pack_bf16(vr[0][1], vr[1][1]);
      pk.z = pack_bf16(vr[0][2], vr[1][2]);
      pk.w = pack_bf16(vr[0][3], vr[1][3]);
      *(u32x4*)(vdst + (size_t)(cg * 4 + pp) * DHW) = pk;
    }
  } else {
    // ---------- general 4-tap fallback (cold): recompute per (pair, px)
#pragma unroll 1
    for (int pp = 0; pp < 4; ++pp) {
      float vr[2][4];
#pragma unroll 1
      for (int j = 0; j < 4; ++j) {
        float xf = (float)(x4 + j);
        int ci[16]; float cwt[16];
#pragma unroll
        for (int v = 0; v < 4; ++v) {
          const float* m = M + v * 12;
          float rx = m[0] * xf + m[1] * yf + m[2];
          float ry = m[3] * xf + m[4] * yf + m[5];
          float rz = m[6] * xf + m[7] * yf + m[8];
          float px = rx * df + m[9];
          float py = ry * df + m[10];
          float pz = rz * df + m[11];
          float gx = px / pz;
          float gy = py / pz;
          float x0 = floorf(gx), y0 = floorf(gy);
          float wx = gx - x0, wy = gy - y0;
          float cxs[2] = {x0, x0 + 1.f}, cys[2] = {y0, y0 + 1.f};
          float wxs[2] = {1.f - wx, wx}, wys[2] = {1.f - wy, wy};
#pragma unroll
          for (int cy = 0; cy < 2; ++cy)
#pragma unroll
            for (int cx = 0; cx < 2; ++cx) {
              float fx = cxs[cx], fy = cys[cy];
              bool valid = (fx >= 0.f) && (fx <= (float)(NW - 1)) &&
                           (fy >= 0.f) && (fy <= (float)(NH - 1));
              float fxc = fminf(fmaxf(fx, 0.f), (float)(NW - 1));
              float fyc = fminf(fmaxf(fy, 0.f), (float)(NH - 1));
              int xi = (int)fxc, yi = (int)fyc;
              ci[v * 4 + cy * 2 + cx] = yi * WPAD + xi;   // padded stride
              cwt[v * 4 + cy * 2 + cx] = wxs[cx] * wys[cy] * (valid ? 1.f : 0.f);
            }
        }
#pragma unroll
        for (int cc = 0; cc < 2; ++cc) {
          int c = c0 + pp * 2 + cc;
          float f0 = fpad[(size_t)c * HWP + y * WPAD + x4 + j];
          float vs = f0, vq = f0 * f0;
#pragma unroll
          for (int v = 0; v < 4; ++v) {
            const float* pl = fpad + (size_t)((v + 1) * NC + c) * HWP;
            float val = cwt[v * 4 + 0] * pl[ci[v * 4 + 0]]
                      + cwt[v * 4 + 1] * pl[ci[v * 4 + 1]]
                      + cwt[v * 4 + 2] * pl[ci[v * 4 + 2]]
                      + cwt[v * 4 + 3] * pl[ci[v * 4 + 3]];
            vs += val;
            vq += val * val;
          }
          vr[cc][j] = vq * 0.2f - (vs * 0.2f) * (vs * 0.2f);
        }
      }
      u32x4 pk;
      pk.x = pack_bf16(vr[0][0], vr[1][0]);
      pk.y = pack_bf16(vr[0][1], vr[1][1]);
      pk.z = pack_bf16(vr[0][2], vr[1][2]);
      pk.w = pack_bf16(vr[0][3], vr[1][3]);
      *(u32x4*)(vdst + (size_t)(cg * 4 + pp) * DHW) = pk;
    }
  }
}

// --------------------------------- K2b: contraction GEMM (27x32)x(32xDHW)
__global__ __launch_bounds__(256) void k_contract(
    const uint32_t* __restrict__ varP,       // [16][DHW] bf16 pairs
    const unsigned short* __restrict__ wfB,  // [2][64][8] bf16 fragments
    unsigned short* __restrict__ WVu)        // [27][DHW] bf16
{
  int tid = threadIdx.x;
  int lane = tid & 63;
  int wavebase = blockIdx.x * 256 + (tid & ~63);
  short8 bfr0 = *(const short8*)(wfB + (size_t)lane * 8);
  short8 bfr1 = *(const short8*)(wfB + (size_t)(64 + lane) * 8);
  int lr = lane & 15, lk = lane >> 4;
  uint32_t* W32 = (uint32_t*)WVu;

#pragma unroll
  for (int m = 0; m < 4; ++m) {
    int voxA = wavebase + m * 16 + lr;
    u32x4 q;
    q.x = varP[(size_t)(lk * 4 + 0) * DHW + voxA];
    q.y = varP[(size_t)(lk * 4 + 1) * DHW + voxA];
    q.z = varP[(size_t)(lk * 4 + 2) * DHW + voxA];
    q.w = varP[(size_t)(lk * 4 + 3) * DHW + voxA];
    short8 af;
    __builtin_memcpy(&af, &q, 16);            // k ascending: pairs in order
    f32x4 z = {0.f, 0.f, 0.f, 0.f};
    f32x4 a0 = __builtin_amdgcn_mfma_f32_16x16x32_bf16(af, bfr0, z, 0, 0, 0);
    f32x4 a1 = __builtin_amdgcn_mfma_f32_16x16x32_bf16(af, bfr1, z, 0, 0, 0);
    int v4 = wavebase + m * 16 + lk * 4;
    size_t o0 = ((size_t)lr * DHW + v4) >> 1;
    W32[o0] = pack_bf16(a0[0], a0[1]);
    W32[o0 + 1] = pack_bf16(a0[2], a0[3]);
    int tap1 = 16 + lr;
    if (tap1 < 27) {
      size_t o1 = ((size_t)tap1 * DHW + v4) >> 1;
      W32[o1] = pack_bf16(a1[0], a1[1]);
      W32[o1 + 1] = pack_bf16(a1[2], a1[3]);
    }
  }
}

// ------------------------------------------------- K3a: 27-tap gather (conv)
__global__ __launch_bounds__(256) void k_conv(const __hip_bfloat16* __restrict__ WV,
                                              float* __restrict__ pre) {
  int idx = blockIdx.x * 256 + threadIdx.x;
  int x = idx % NW;
  int t1 = idx / NW;
  int y = t1 % NH;
  int d = t1 / NH;
  float acc = 0.f;
#pragma unroll
  for (int dd = 0; dd < 3; ++dd) {
    int dp = d + dd - 1;
    bool dok = (dp >= 0) && (dp < ND);
    int dpc = min(max(dp, 0), ND - 1);
#pragma unroll
    for (int i = 0; i < 3; ++i) {
      int yp = y + i - 1;
      bool yok = (yp >= 0) && (yp < NH);
      int ypc = min(max(yp, 0), NH - 1);
#pragma unroll
      for (int j = 0; j < 3; ++j) {
        int xp = x + j - 1;
        bool xok = (xp >= 0) && (xp < NW);
        int xpc = min(max(xp, 0), NW - 1);
        int t = dd * 9 + i * 3 + j;
        float v = __bfloat162float(WV[t * DHW + dpc * HW + ypc * NW + xpc]);
        acc += (dok && yok && xok) ? v : 0.f;
      }
    }
  }
  pre[idx] = acc;
}

// ---------------------------------------- K3b: softmax over D + depth + conf
__global__ __launch_bounds__(256) void k_softmax(const float* __restrict__ pre,
                                                 const float* __restrict__ depthv,
                                                 float* __restrict__ depthf,
                                                 float* __restrict__ out_depth,
                                                 float* __restrict__ out_conf) {
  int p = blockIdx.x * 256 + threadIdx.x;
  float pr[ND];
  float m = -1e30f;
#pragma unroll
  for (int d = 0; d < ND; ++d) { pr[d] = pre[d * HW + p]; m = fmaxf(m, pr[d]); }
  float s = 0.f;
#pragma unroll
  for (int d = 0; d < ND; ++d) { pr[d] = expf(pr[d] - m); s += pr[d]; }
  float inv = 1.f / s;
  float dep = 0.f, ti = 0.f;
#pragma unroll
  for (int d = 0; d < ND; ++d) {
    float prob = pr[d] * inv;
    pr[d] = prob;
    dep += prob * depthv[d];
    ti += prob * (float)d;
  }
  int di = (int)ti;
  di = di < 0 ? 0 : (di > ND - 1 ? ND - 1 : di);
  float conf = 0.f;
#pragma unroll
  for (int d = 0; d < ND; ++d)
    conf += (d >= di - 1 && d <= di + 2) ? pr[d] : 0.f;
  depthf[p] = dep;
  out_depth[p] = dep;
  out_conf[p] = conf;
}

// -------------------------------------------------- K4: convex upsample (x8)
// 8 outputs (dx 0..7) per thread — the R6 version (others-best config).
__global__ __launch_bounds__(256) void k_upsample(const float* __restrict__ mask,
                                                  const float* __restrict__ depthf,
                                                  float* __restrict__ out) {
  int idx = blockIdx.x * 256 + threadIdx.x;  // [0, HW*8)
  int x = idx % NW;
  int r = idx / NW;
  int y = r % NH;
  int dy = r / NH;                           // 0..7
  int pix = y * NW + x;

  float dv[9];
#pragma unroll
  for (int k = 0; k < 9; ++k) {
    int ky = y + k / 3 - 1;
    int kx = x + k % 3 - 1;
    bool ok = (ky >= 0) && (ky < NH) && (kx >= 0) && (kx < NW);
    int kyc = min(max(ky, 0), NH - 1);
    int kxc = min(max(kx, 0), NW - 1);
    float t = depthf[kyc * NW + kxc];
    dv[k] = ok ? t : 0.f;
  }

  float res[8];
#pragma unroll
  for (int dx = 0; dx < 8; ++dx) {
    float mv[9];
    float mmax = -1e30f;
#pragma unroll
    for (int k = 0; k < 9; ++k) {
      mv[k] = mask[(size_t)(k * 64 + dy * 8 + dx) * HW + pix];
      mmax = fmaxf(mmax, mv[k]);
    }
    float s = 0.f, acc = 0.f;
#pragma unroll
    for (int k = 0; k < 9; ++k) {
      float e = expf(mv[k] - mmax);
      s += e;
      acc += e * dv[k];
    }
    res[dx] = acc / s;
  }

  float* op = out + (size_t)(y * 8 + dy) * (NW * 8) + x * 8;
  f32x4 lo, hi;
  lo.x = res[0]; lo.y = res[1]; lo.z = res[2]; lo.w = res[3];
  hi.x = res[4]; hi.y = res[5]; hi.z = res[6]; hi.w = res[7];
  *(f32x4*)op = lo;
  *(f32x4*)(op + 4) = hi;
}

// ---------------------------------------------------------------- launcher
extern "C" void kernel_launch(void* const* d_in, const int* in_sizes, int n_in,
                              void* d_out, int out_size, void* d_ws, size_t ws_size,
                              hipStream_t stream) {
  const float* feat   = (const float*)d_in[0];
  const float* proj   = (const float*)d_in[1];
  const float* depthv = (const float*)d_in[2];
  const float* mask   = (const float*)d_in[3];
  const float* wreg   = (const float*)d_in[4];

  char* ws = (char*)d_ws;
  float* M       = (float*)(ws + OFF_M);
  unsigned short* wfB = (unsigned short*)(ws + OFF_WFB);
  float* depthf  = (float*)(ws + OFF_DEPTHF);
  float* pre     = (float*)(ws + OFF_PRE);
  float* fpad    = (float*)(ws + OFF_FPAD);    // aliases WV (dead by contract)
  uint32_t* varP = (uint32_t*)(ws + OFF_VARP);
  unsigned short* WVu = (unsigned short*)(ws + OFF_WV);
  const __hip_bfloat16* WV = (const __hip_bfloat16*)(ws + OFF_WV);

  float* out = (float*)d_out;
  float* out_depth = out + (NH * 8) * (NW * 8);
  float* out_conf  = out_depth + HW;

  k_setup<<<1, 64, 0, stream>>>(proj, wreg, M, wfB);
  k_pad<<<(NV * NC * HWP) / 256, 256, 0, stream>>>(feat, fpad);
  k_gather<<<DHW / 256, 256, 0, stream>>>(fpad, depthv, M, varP);
  k_contract<<<DHW / 256, 256, 0, stream>>>(varP, wfB, WVu);
  k_conv<<<DHW / 256, 256, 0, stream>>>(WV, pre);
  k_softmax<<<HW / 256, 256, 0, stream>>>(pre, depthv, depthf, out_depth, out_conf);
  k_upsample<<<(NH * 8 * NW * 8 / 8) / 256, 256, 0, stream>>>(mask, depthf, out);
}

// Round 10
// 226.144 us; speedup vs baseline: 1.5718x; 1.5718x over previous
//
#include <hip/hip_runtime.h>
#include <hip/hip_bf16.h>

// Effi_MVS: B=1, V=5, C=32, D=48, H=128, W=160, RATIO=8.
// Round 13: recombination of proven-best components after 5 consecutive
// failed gather restructures (R7 LDS, R9 MFMA, R10 sched, R11 split, R12
// uniform-shift) — R8's fused gather (110us) is a local optimum.
//   - k_warpvar: R8 exact (VGPR 68, ~110us measured twice).
//   - k_conv: R6 exact scalar (the 102us-others config; 8-wide cost +13).
//   - k_upsample: 8-out version (in both best configs).
//   - k_softmax: NEW — depth split 4x12 across adjacent lanes + shfl_xor
//     reductions. 80 -> 320 blocks (was 0.3 blocks/CU, the most TLP-starved
//     kernel in the pipeline; TLP decided every experiment this session).

#define NV 5
#define NC 32
#define ND 48
#define NH 128
#define NW 160
#define HW (NH * NW)
#define DHW (ND * HW)

typedef __attribute__((ext_vector_type(2))) float f32x2;
typedef __attribute__((ext_vector_type(4))) float f32x4;
typedef __attribute__((ext_vector_type(2), aligned(4))) float f32x2u;

// ws layout (bytes)
#define OFF_M      0          // float M[4][12]
#define OFF_WF     256        // float wf[32][28]
#define OFF_DEPTHF 4096       // float depthf[20480]
#define OFF_PRE    86016      // float pre[48*128*160]
#define OFF_WV     4018176    // bf16 WV[27][48*128*160]
// total = 57,102,336 bytes

// ---------------------------------------------------------------- K1: setup
__global__ void k_setup(const float* __restrict__ proj,
                        const float* __restrict__ wreg,
                        float* __restrict__ M, float* __restrict__ wf) {
  if (threadIdx.x != 0) return;
  double P[NV][2][4][4];
  for (int v = 0; v < NV; ++v)
    for (int m = 0; m < 2; ++m)
      for (int i = 0; i < 4; ++i)
        for (int j = 0; j < 4; ++j)
          P[v][m][i][j] = (double)proj[((v * 2 + m) * 4 + i) * 4 + j];
  double C[NV][4][4];
  for (int v = 0; v < NV; ++v) {
    for (int i = 0; i < 4; ++i)
      for (int j = 0; j < 4; ++j) C[v][i][j] = P[v][0][i][j];
    for (int i = 0; i < 3; ++i)
      for (int j = 0; j < 4; ++j) {
        double s = 0.0;
        for (int k = 0; k < 3; ++k) s += P[v][1][i][k] * P[v][0][k][j];
        C[v][i][j] = s;
      }
  }
  double a[4][8];
  for (int i = 0; i < 4; ++i)
    for (int j = 0; j < 4; ++j) { a[i][j] = C[0][i][j]; a[i][j + 4] = (i == j) ? 1.0 : 0.0; }
  for (int col = 0; col < 4; ++col) {
    int piv = col; double best = fabs(a[col][col]);
    for (int r = col + 1; r < 4; ++r) { double v = fabs(a[r][col]); if (v > best) { best = v; piv = r; } }
    if (piv != col)
      for (int j = 0; j < 8; ++j) { double t = a[col][j]; a[col][j] = a[piv][j]; a[piv][j] = t; }
    double pv = a[col][col];
    for (int j = 0; j < 8; ++j) a[col][j] /= pv;
    for (int r = 0; r < 4; ++r) if (r != col) {
      double f = a[r][col];
      for (int j = 0; j < 8; ++j) a[r][j] -= f * a[col][j];
    }
  }
  double inv[4][4];
  for (int i = 0; i < 4; ++i)
    for (int j = 0; j < 4; ++j) inv[i][j] = a[i][j + 4];
  for (int v = 1; v < NV; ++v) {
    float* m = M + (v - 1) * 12;
    for (int i = 0; i < 3; ++i) {
      double r[4] = {0, 0, 0, 0};
      for (int k = 0; k < 4; ++k) {
        double cv = C[v][i][k];
        for (int j = 0; j < 4; ++j) r[j] += cv * inv[k][j];
      }
      m[i * 3 + 0] = (float)r[0]; m[i * 3 + 1] = (float)r[1]; m[i * 3 + 2] = (float)r[2];
      m[9 + i] = (float)r[3];
    }
  }
  for (int c = 0; c < NC; ++c) {
    for (int t = 0; t < 27; ++t) wf[c * 28 + t] = wreg[c * 27 + t];
    wf[c * 28 + 27] = 0.f;
  }
}

// ------------------------------------------- K2: warp + variance + contract
// R8's exact version: 110us measured (R8 and R10 runs).
__global__ __launch_bounds__(256) void k_warpvar(
    const float* __restrict__ feat,    // [5][32][128][160]
    const float* __restrict__ depthv,  // [48]
    const float* __restrict__ M,       // [4][12]
    const float* __restrict__ wf,      // [32][28]
    __hip_bfloat16* __restrict__ WV)   // [27][DHW]
{
  int idx = blockIdx.x * 256 + threadIdx.x;   // [0, DHW)
  int x = idx % NW;
  int t1 = idx / NW;
  int y = t1 % NH;
  int d = t1 / NH;
  int pix = y * NW + x;
  float xf = (float)x, yf = (float)y;
  float df = depthv[d];

  int   off[4];
  float wA[4], wB[4];
  bool any4 = false;

#pragma unroll
  for (int v = 0; v < 4; ++v) {
    const float* m = M + v * 12;
    float rx = m[0] * xf + m[1] * yf + m[2];
    float ry = m[3] * xf + m[4] * yf + m[5];
    float rz = m[6] * xf + m[7] * yf + m[8];
    float px = rx * df + m[9];
    float py = ry * df + m[10];
    float pz = rz * df + m[11];
    float gx = px / pz;
    float gy = py / pz;
    float y0 = floorf(gy);
    float wy = gy - y0;
    bool two = (wy == 0.f) || (wy == 1.f);
    any4 = any4 || !two;
    float rowf = (wy == 0.f) ? y0 : (y0 + 1.f);  // single surviving y-row
    float x0 = floorf(gx);
    float wx = gx - x0;
    bool yok  = (rowf >= 0.f) && (rowf <= (float)(NH - 1));
    bool x0ok = (x0 >= 0.f) && (x0 <= (float)(NW - 1)) && yok;
    bool x1ok = (x0 >= -1.f) && (x0 <= (float)(NW - 2)) && yok;
    float rc = fminf(fmaxf(rowf, 0.f), (float)(NH - 1));
    float xc = fminf(fmaxf(x0, 0.f), (float)(NW - 1));
    int xi = (int)xc;
    int o = (int)rc * NW + xi;
    bool ddv = (o == HW - 1);          // absolute plane end: shift base by 1
    bool sv  = (x0 >= 0.f) && (xi <= NW - 2);  // e.y is a distinct valid tap1
    o -= ddv ? 1 : 0;
    float w0 = (1.f - wx) * (x0ok ? 1.f : 0.f);
    float w1 = wx * (x1ok ? 1.f : 0.f);
    float wsum = w0 + w1;
    wA[v] = ddv ? 0.f : (sv ? w0 : wsum);
    wB[v] = ddv ? wsum : (sv ? w1 : 0.f);
    off[v] = o;
  }

  f32x2 wv[14];
#pragma unroll
  for (int u = 0; u < 14; ++u) { wv[u].x = 0.f; wv[u].y = 0.f; }

  if (__builtin_expect(any4, 0)) {
    // ---------- general 4-tap fallback (cold). v/u unrolled, c rolled.
    int cidx[16]; float cw[16];
#pragma unroll
    for (int v = 0; v < 4; ++v) {
      const float* m = M + v * 12;
      float rx = m[0] * xf + m[1] * yf + m[2];
      float ry = m[3] * xf + m[4] * yf + m[5];
      float rz = m[6] * xf + m[7] * yf + m[8];
      float px = rx * df + m[9];
      float py = ry * df + m[10];
      float pz = rz * df + m[11];
      float gx = px / pz;
      float gy = py / pz;
      float x0 = floorf(gx), y0 = floorf(gy);
      float wx = gx - x0, wy = gy - y0;
      float cxs[2] = {x0, x0 + 1.f}, cys[2] = {y0, y0 + 1.f};
      float wxs[2] = {1.f - wx, wx}, wys[2] = {1.f - wy, wy};
#pragma unroll
      for (int cy = 0; cy < 2; ++cy)
#pragma unroll
        for (int cx = 0; cx < 2; ++cx) {
          float fx = cxs[cx], fy = cys[cy];
          bool valid = (fx >= 0.f) && (fx <= (float)(NW - 1)) &&
                       (fy >= 0.f) && (fy <= (float)(NH - 1));
          float fxc = fminf(fmaxf(fx, 0.f), (float)(NW - 1));
          float fyc = fminf(fmaxf(fy, 0.f), (float)(NH - 1));
          int xi2 = (int)fxc, yi2 = (int)fyc;
          cidx[v * 4 + cy * 2 + cx] = yi2 * NW + xi2;
          cw[v * 4 + cy * 2 + cx] = wxs[cx] * wys[cy] * (valid ? 1.f : 0.f);
        }
    }
    for (int c = 0; c < NC; ++c) {
      float f0 = feat[c * HW + pix];
      float vs = f0, vq = f0 * f0;
#pragma unroll
      for (int v = 0; v < 4; ++v) {
        const float* fv = feat + ((v + 1) * NC + c) * HW;
        float val = cw[v * 4 + 0] * fv[cidx[v * 4 + 0]]
                  + cw[v * 4 + 1] * fv[cidx[v * 4 + 1]]
                  + cw[v * 4 + 2] * fv[cidx[v * 4 + 2]]
                  + cw[v * 4 + 3] * fv[cidx[v * 4 + 3]];
        vs += val;
        vq += val * val;
      }
      float var = vq * 0.2f - (vs * 0.2f) * (vs * 0.2f);
      const f32x2* wrow = (const f32x2*)(wf + c * 28);
      f32x2 vv; vv.x = var; vv.y = var;
#pragma unroll
      for (int u = 0; u < 14; ++u) wv[u] += wrow[u] * vv;
    }
  } else {
    // ---------- hot 2-tap path, 8-channel load batches for MLP
#pragma unroll
    for (int g = 0; g < NC; g += 8) {
      float f0[8];
      f32x2 e[8][4];
#pragma unroll
      for (int cc = 0; cc < 8; ++cc) {
        int c = g + cc;
        f0[cc] = feat[c * HW + pix];
#pragma unroll
        for (int v = 0; v < 4; ++v) {
          const float* fv = feat + ((v + 1) * NC + c) * HW;
          f32x2u t = *(const f32x2u*)(fv + off[v]);
          e[cc][v].x = t.x; e[cc][v].y = t.y;
        }
      }
#pragma unroll
      for (int cc = 0; cc < 8; ++cc) {
        int c = g + cc;
        float vs = f0[cc], vq = f0[cc] * f0[cc];
#pragma unroll
        for (int v = 0; v < 4; ++v) {
          float val = wA[v] * e[cc][v].x + wB[v] * e[cc][v].y;
          vs += val;
          vq += val * val;
        }
        float var = vq * 0.2f - (vs * 0.2f) * (vs * 0.2f);
        const f32x2* wrow = (const f32x2*)(wf + c * 28);
        f32x2 vv; vv.x = var; vv.y = var;
#pragma unroll
        for (int u = 0; u < 14; ++u) wv[u] += wrow[u] * vv;
      }
    }
  }

#pragma unroll
  for (int u = 0; u < 14; ++u) {
    int t0 = 2 * u;
    WV[t0 * DHW + idx] = __float2bfloat16(wv[u].x);
    if (t0 + 1 < 27) WV[(t0 + 1) * DHW + idx] = __float2bfloat16(wv[u].y);
  }
}

// ------------------------------------------------- K3a: 27-tap gather (conv)
// Scalar version (the R6 102us-others config; TLP > per-thread efficiency).
__global__ __launch_bounds__(256) void k_conv(const __hip_bfloat16* __restrict__ WV,
                                              float* __restrict__ pre) {
  int idx = blockIdx.x * 256 + threadIdx.x;
  int x = idx % NW;
  int t1 = idx / NW;
  int y = t1 % NH;
  int d = t1 / NH;
  float acc = 0.f;
#pragma unroll
  for (int dd = 0; dd < 3; ++dd) {
    int dp = d + dd - 1;
    bool dok = (dp >= 0) && (dp < ND);
    int dpc = min(max(dp, 0), ND - 1);
#pragma unroll
    for (int i = 0; i < 3; ++i) {
      int yp = y + i - 1;
      bool yok = (yp >= 0) && (yp < NH);
      int ypc = min(max(yp, 0), NH - 1);
#pragma unroll
      for (int j = 0; j < 3; ++j) {
        int xp = x + j - 1;
        bool xok = (xp >= 0) && (xp < NW);
        int xpc = min(max(xp, 0), NW - 1);
        int t = dd * 9 + i * 3 + j;
        float v = __bfloat162float(WV[t * DHW + dpc * HW + ypc * NW + xpc]);
        acc += (dok && yok && xok) ? v : 0.f;
      }
    }
  }
  pre[idx] = acc;
}

// -------------------- K3b: softmax over D (split 4x12 across adjacent lanes)
__global__ __launch_bounds__(256) void k_softmax(const float* __restrict__ pre,
                                                 const float* __restrict__ depthv,
                                                 float* __restrict__ depthf,
                                                 float* __restrict__ out_depth,
                                                 float* __restrict__ out_conf) {
  int t = blockIdx.x * 256 + threadIdx.x;    // [0, HW*4)
  int p = t >> 2;
  int q = t & 3;                             // depth quarter (12 depths each)
  float pr[12];
  float m = -1e30f;
#pragma unroll
  for (int i = 0; i < 12; ++i) {
    pr[i] = pre[(q * 12 + i) * HW + p];
    m = fmaxf(m, pr[i]);
  }
  m = fmaxf(m, __shfl_xor(m, 1, 64));
  m = fmaxf(m, __shfl_xor(m, 2, 64));
  float s = 0.f, sd = 0.f, si = 0.f;
#pragma unroll
  for (int i = 0; i < 12; ++i) {
    float e = expf(pr[i] - m);
    pr[i] = e;
    int d = q * 12 + i;
    s  += e;
    sd += e * depthv[d];
    si += e * (float)d;
  }
  s  += __shfl_xor(s, 1, 64);  s  += __shfl_xor(s, 2, 64);
  sd += __shfl_xor(sd, 1, 64); sd += __shfl_xor(sd, 2, 64);
  si += __shfl_xor(si, 1, 64); si += __shfl_xor(si, 2, 64);
  float inv = 1.f / s;
  float dep = sd * inv;
  float ti  = si * inv;
  int di = (int)ti;                          // truncation, matches astype(int32)
  di = di < 0 ? 0 : (di > ND - 1 ? ND - 1 : di);
  float conf = 0.f;
#pragma unroll
  for (int i = 0; i < 12; ++i) {
    int d = q * 12 + i;
    conf += (d >= di - 1 && d <= di + 2) ? pr[i] * inv : 0.f;
  }
  conf += __shfl_xor(conf, 1, 64);
  conf += __shfl_xor(conf, 2, 64);
  if (q == 0) {
    depthf[p] = dep;
    out_depth[p] = dep;
    out_conf[p] = conf;
  }
}

// -------------------------------------------------- K4: convex upsample (x8)
// 8 outputs (dx 0..7) per thread — in both best-others configs.
__global__ __launch_bounds__(256) void k_upsample(const float* __restrict__ mask,
                                                  const float* __restrict__ depthf,
                                                  float* __restrict__ out) {
  int idx = blockIdx.x * 256 + threadIdx.x;  // [0, HW*8)
  int x = idx % NW;
  int r = idx / NW;
  int y = r % NH;
  int dy = r / NH;                           // 0..7
  int pix = y * NW + x;

  float dv[9];
#pragma unroll
  for (int k = 0; k < 9; ++k) {
    int ky = y + k / 3 - 1;
    int kx = x + k % 3 - 1;
    bool ok = (ky >= 0) && (ky < NH) && (kx >= 0) && (kx < NW);
    int kyc = min(max(ky, 0), NH - 1);
    int kxc = min(max(kx, 0), NW - 1);
    float t = depthf[kyc * NW + kxc];
    dv[k] = ok ? t : 0.f;
  }

  float res[8];
#pragma unroll
  for (int dx = 0; dx < 8; ++dx) {
    float mv[9];
    float mmax = -1e30f;
#pragma unroll
    for (int k = 0; k < 9; ++k) {
      mv[k] = mask[(size_t)(k * 64 + dy * 8 + dx) * HW + pix];
      mmax = fmaxf(mmax, mv[k]);
    }
    float s = 0.f, acc = 0.f;
#pragma unroll
    for (int k = 0; k < 9; ++k) {
      float e = expf(mv[k] - mmax);
      s += e;
      acc += e * dv[k];
    }
    res[dx] = acc / s;
  }

  float* op = out + (size_t)(y * 8 + dy) * (NW * 8) + x * 8;
  f32x4 lo, hi;
  lo.x = res[0]; lo.y = res[1]; lo.z = res[2]; lo.w = res[3];
  hi.x = res[4]; hi.y = res[5]; hi.z = res[6]; hi.w = res[7];
  *(f32x4*)op = lo;
  *(f32x4*)(op + 4) = hi;
}

// ---------------------------------------------------------------- launcher
extern "C" void kernel_launch(void* const* d_in, const int* in_sizes, int n_in,
                              void* d_out, int out_size, void* d_ws, size_t ws_size,
                              hipStream_t stream) {
  const float* feat   = (const float*)d_in[0];
  const float* proj   = (const float*)d_in[1];
  const float* depthv = (const float*)d_in[2];
  const float* mask   = (const float*)d_in[3];
  const float* wreg   = (const float*)d_in[4];

  char* ws = (char*)d_ws;
  float* M       = (float*)(ws + OFF_M);
  float* wf      = (float*)(ws + OFF_WF);
  float* depthf  = (float*)(ws + OFF_DEPTHF);
  float* pre     = (float*)(ws + OFF_PRE);
  __hip_bfloat16* WV = (__hip_bfloat16*)(ws + OFF_WV);

  float* out = (float*)d_out;
  float* out_depth = out + (NH * 8) * (NW * 8);
  float* out_conf  = out_depth + HW;

  k_setup<<<1, 64, 0, stream>>>(proj, wreg, M, wf);
  k_warpvar<<<DHW / 256, 256, 0, stream>>>(feat, depthv, M, wf, WV);
  k_conv<<<DHW / 256, 256, 0, stream>>>(WV, pre);
  k_softmax<<<(HW * 4) / 256, 256, 0, stream>>>(pre, depthv, depthf, out_depth, out_conf);
  k_upsample<<<(NH * 8 * NW * 8 / 8) / 256, 256, 0, stream>>>(mask, depthf, out);
}